// Round 11
// baseline (2615.319 us; speedup 1.0000x reference)
//
#include <hip/hip_runtime.h>

typedef _Float16 half8 __attribute__((ext_vector_type(8)));
typedef float floatx4 __attribute__((ext_vector_type(4)));

#define NB 256    // batch
#define NT 512    // time
#define NI 64     // input
#define NH 256    // hidden
#define NSEQ 16   // sequences per block
#define NBLK (NB / NSEQ)   // 16 blocks
#define THR 1024           // 16 waves
#define HS 344             // H row stride in f16

// B-fragment pack (VALIDATED R9/R10): frags 0..479 as before; 480..487 = o-tile
// (w_out replicated into all 16 cols, K 0..255).
// wb[f*512 + lane*8 + i] = W[k = kb*32 + (lane>>4)*8 + i][n = tt*16 + (lane&15)]
#define WB_N (488 * 512)

__global__ __launch_bounds__(256) void gru_prep_kernel(
    const float* __restrict__ w_ih, const float* __restrict__ w_hh,
    const float* __restrict__ w_out, _Float16* __restrict__ wb)
{
  int n = blockIdx.x * 256 + threadIdx.x;
  if (n >= WB_N) return;
  int i = n & 7, l = (n >> 3) & 63, f = n >> 9;
  int q = l >> 4, col = l & 15;
  float v;
  if (f < 480) {
    int tt, kb, gate;
    if (f < 160)      { tt = f / 10;               kb = f % 10;        gate = 0; }
    else if (f < 320) { int f2 = f - 160; tt = f2 / 10; kb = f2 % 10;  gate = 1; }
    else if (f < 448) { int f3 = f - 320; tt = f3 / 8;  kb = f3 % 8;   gate = 2; }
    else              { int f4 = f - 448; tt = f4 / 2;  kb = 8 + (f4 & 1); gate = 3; }
    int j = (tt & 15) * 16 + col;
    int k = kb * 32 + q * 8 + i;
    if (gate == 0)      v = (k < 256) ? w_hh[(0   + j) * 256 + k] : w_ih[(0   + j) * 64 + (k - 256)];
    else if (gate == 1) v = (k < 256) ? w_hh[(256 + j) * 256 + k] : w_ih[(256 + j) * 64 + (k - 256)];
    else if (gate == 2) v = w_hh[(512 + j) * 256 + k];
    else                v = w_ih[(512 + j) * 64 + (k - 256)];
  } else {
    int kb = f - 480;                 // o-tile: same value in every col
    int k = kb * 32 + q * 8 + i;
    v = w_out[k];
  }
  wb[n] = (_Float16)v;
}

__device__ __forceinline__ float sigm(float v) {
  return __builtin_amdgcn_rcpf(1.0f + __expf(-v));
}
__device__ __forceinline__ float tanh_f(float v) {
  return 1.0f - 2.0f * __builtin_amdgcn_rcpf(1.0f + __expf(2.0f * v));
}

#define MFMA16(a, b, c) __builtin_amdgcn_mfma_f32_16x16x32_f16(a, b, c, 0, 0, 0)

// ---------------- batched MFMA recurrence: 1 block = 16 sequences ----------------
// R10 skeleton (validated) + out-projection folded into the GEMM as an extra
// o-tile on wave 15 (computes out[t-1] from H=h_{t-1}) — removes the per-step
// shfl reduction / red round-trip / finalize from all waves.
__global__ __launch_bounds__(THR) void gru_kernel(
    const float* __restrict__ x,      // [B, T, I]
    const float* __restrict__ b_ih,   // [768]
    const float* __restrict__ b_hh,   // [768]
    const float* __restrict__ b_out,  // [1]
    const _Float16* __restrict__ wb,  // packed B fragments
    float* __restrict__ out)          // [T, B]
{
  __shared__ __align__(16) _Float16 H[2][NSEQ][HS];   // 22016 B, double-buffered
  __shared__ __align__(16) _Float16 WN[8 * 16 * 512]; // 131072 B: n-gate frags
  __shared__ __align__(16) _Float16 WO[8 * 512];      // 8192 B: o-tile frags

  const int tid  = threadIdx.x;
  const int lane = tid & 63;
  const int w    = tid >> 6;        // wave 0..15
  const int q    = lane >> 4;       // quad 0..3
  const int col  = lane & 15;
  const int b0   = blockIdx.x * NSEQ;
  const int j    = w * 16 + col;    // hidden unit owned in epilogue

  // ---- stage n-gate + o frags to LDS (coalesced float4) ----
  {
    const float4* src = (const float4*)(wb + 320 * 512);
    float4* dst = (float4*)WN;
    #pragma unroll
    for (int it = 0; it < 8; ++it) dst[tid + it * THR] = src[tid + it * THR];
  }
  if (tid < 512) {
    ((float4*)WO)[tid] = ((const float4*)(wb + (size_t)480 * 512))[tid];
  }

  // ---- persistent B fragments: 16 named half8 (64 VGPRs) ----
  const _Float16* wbL = wb + (size_t)lane * 8;
#define LBR(k) const half8 BR##k = *(const half8*)(wbL + (size_t)(w * 10 + (k)) * 512);
  LBR(0) LBR(1) LBR(2) LBR(3) LBR(4) LBR(5) LBR(6) LBR(7) LBR(8) LBR(9)
#undef LBR
#define LBZ(k) const half8 BZ##k = *(const half8*)(wbL + (size_t)(160 + w * 10 + (k)) * 512);
  LBZ(0) LBZ(1) LBZ(2) LBZ(3) LBZ(4) LBZ(5)
#undef LBZ
  const half8* sZ6 = (const half8*)(wbL + (size_t)(160 + w * 10 + 6) * 512);
  const half8* sZ7 = (const half8*)(wbL + (size_t)(160 + w * 10 + 7) * 512);
  const half8* sZ8 = (const half8*)(wbL + (size_t)(160 + w * 10 + 8) * 512);
  const half8* sZ9 = (const half8*)(wbL + (size_t)(160 + w * 10 + 9) * 512);
  const half8* sI0 = (const half8*)(wbL + (size_t)(448 + w * 2 + 0) * 512);
  const half8* sI1 = (const half8*)(wbL + (size_t)(448 + w * 2 + 1) * 512);

  const float br   = b_ih[j] + b_hh[j];
  const float bz   = b_ih[256 + j] + b_hh[256 + j];
  const float bin_ = b_ih[512 + j];
  const float bhn  = b_hh[512 + j];
  const float bo   = b_out[0];

  // ---- init: zero H (both buffers), then x(t=0) into H[0] ----
  {
    float4* hz = (float4*)H;
    #pragma unroll
    for (int it = 0; it < 2; ++it) {
      int idx = tid + it * THR;
      if (idx < (int)(sizeof(H) / 16)) hz[idx] = float4{0, 0, 0, 0};
    }
  }
  __syncthreads();
  H[0][tid >> 6][256 + (tid & 63)] =
      (_Float16)x[(size_t)(b0 + (tid >> 6)) * (NT * NI) + (tid & 63)];
  float h0 = 0.0f, h1 = 0.0f, h2 = 0.0f, h3 = 0.0f;
  const float* xp = x + (size_t)(b0 + (tid >> 6)) * (NT * NI) + 64 + (tid & 63);
  __syncthreads();

  for (int t = 0; t < NT; ++t) {
    const int cur = t & 1, nxt = cur ^ 1;
    half8 SZ6 = *sZ6, SZ7 = *sZ7, SZ8 = *sZ8, SZ9 = *sZ9, SI0i = *sI0, SI1i = *sI1;
    float xv = 0.0f;
    if (t + 1 < NT) xv = xp[(size_t)t * 64];

    // ---- GEMM: A row = seq = col (validated), 30 MFMAs/wave ----
    const _Float16* hrow = &H[cur][col][q * 8];
    floatx4 cR = {0, 0, 0, 0}, cZ = {0, 0, 0, 0}, cN = {0, 0, 0, 0}, cI = {0, 0, 0, 0};
#define KBN(k, BZk) { \
    half8 a = *(const half8*)(hrow + (k) * 32); \
    cR = MFMA16(a, BR##k, cR); \
    cZ = MFMA16(a, BZk, cZ); \
    cN = MFMA16(a, *(const half8*)&WN[(w * 8 + (k)) * 512 + lane * 8], cN); }
    KBN(0, BZ0) KBN(1, BZ1) KBN(2, BZ2) KBN(3, BZ3) KBN(4, BZ4) KBN(5, BZ5)
    KBN(6, SZ6) KBN(7, SZ7)
#undef KBN
    { half8 a = *(const half8*)(hrow + 8 * 32);
      cR = MFMA16(a, BR8, cR); cZ = MFMA16(a, SZ8, cZ); cI = MFMA16(a, SI0i, cI); }
    { half8 a = *(const half8*)(hrow + 9 * 32);
      cR = MFMA16(a, BR9, cR); cZ = MFMA16(a, SZ9, cZ); cI = MFMA16(a, SI1i, cI); }

    // ---- o-tile on wave 15: out[t-1] = h_{t-1} . w_out (H[cur] holds h_{t-1}) ----
    if (w == 15) {
      floatx4 cO = {0, 0, 0, 0};
      #pragma unroll
      for (int kb = 0; kb < 8; ++kb) {
        half8 a = *(const half8*)(hrow + kb * 32);
        cO = MFMA16(a, *(const half8*)&WO[kb * 512 + lane * 8], cO);
      }
      if (col == 0 && t > 0) {
        out[(t - 1) * NB + b0 + q * 4 + 0] = cO[0] + bo;
        out[(t - 1) * NB + b0 + q * 4 + 1] = cO[1] + bo;
        out[(t - 1) * NB + b0 + q * 4 + 2] = cO[2] + bo;
        out[(t - 1) * NB + b0 + q * 4 + 3] = cO[3] + bo;
      }
    }

    // ---- in-register epilogue: lane owns (j, seqs q*4..q*4+3) ----
#define GATE(m, hvar) { \
    float rr = sigm(cR[m] + br); \
    float zz = sigm(cZ[m] + bz); \
    float nn = tanh_f(cI[m] + bin_ + rr * (cN[m] + bhn)); \
    hvar = (1.0f - zz) * nn + zz * hvar; \
    H[nxt][q * 4 + (m)][j] = (_Float16)hvar; }
    GATE(0, h0) GATE(1, h1) GATE(2, h2) GATE(3, h3)
#undef GATE
    if (t + 1 < NT) H[nxt][tid >> 6][256 + (tid & 63)] = (_Float16)xv;

    __syncthreads();   // the single per-step barrier
  }

  // ---- tail: out[NT-1] from h_{NT-1} (in H[0] since NT is even) ----
  if (w == 15) {
    const _Float16* hrow = &H[0][col][q * 8];
    floatx4 cO = {0, 0, 0, 0};
    #pragma unroll
    for (int kb = 0; kb < 8; ++kb) {
      half8 a = *(const half8*)(hrow + kb * 32);
      cO = MFMA16(a, *(const half8*)&WO[kb * 512 + lane * 8], cO);
    }
    if (col == 0) {
      out[(NT - 1) * NB + b0 + q * 4 + 0] = cO[0] + bo;
      out[(NT - 1) * NB + b0 + q * 4 + 1] = cO[1] + bo;
      out[(NT - 1) * NB + b0 + q * 4 + 2] = cO[2] + bo;
      out[(NT - 1) * NB + b0 + q * 4 + 3] = cO[3] + bo;
    }
  }
}

extern "C" void kernel_launch(void* const* d_in, const int* in_sizes, int n_in,
                              void* d_out, int out_size, void* d_ws, size_t ws_size,
                              hipStream_t stream) {
  const float* x     = (const float*)d_in[0];
  const float* w_ih  = (const float*)d_in[1];
  const float* w_hh  = (const float*)d_in[2];
  const float* b_ih  = (const float*)d_in[3];
  const float* b_hh  = (const float*)d_in[4];
  const float* w_out = (const float*)d_in[5];
  const float* b_out = (const float*)d_in[6];
  float* out = (float*)d_out;

  _Float16* wb = (_Float16*)d_ws;   // 488 frags = 500 KB

  gru_prep_kernel<<<(WB_N + 255) / 256, 256, 0, stream>>>(w_ih, w_hh, w_out, wb);
  gru_kernel<<<NBLK, THR, 0, stream>>>(x, b_ih, b_hh, b_out, wb, out);
}

// Round 12
// 1662.886 us; speedup vs baseline: 1.5728x; 1.5728x over previous
//
#include <hip/hip_runtime.h>

typedef _Float16 half8 __attribute__((ext_vector_type(8)));
typedef float floatx4 __attribute__((ext_vector_type(4)));

#define NB 256    // batch
#define NT 512    // time
#define NI 64     // input
#define NH 256    // hidden
#define NSEQ 16   // sequences per block
#define NBLK (NB / NSEQ)   // 16 blocks
#define THR 512            // 8 waves
#define HS 344             // H row stride in f16

// B-fragment pack (VALIDATED R9/R10): 480 frags x 64 lanes x 8 f16.
// Cols: [0,256)=r, [256,512)=z, [512,768)=h_n, [768,1024)=i_n. K: [0,256)=h, [256,320)=x.
// frag f: r: tt*10+kb; z: 160+tt*10+kb; h_n: 320+tt*8+kb (kb<8); i_n: 448+tt*2+(kb-8).
// wb[f*512 + lane*8 + i] = W[k = kb*32 + (lane>>4)*8 + i][n = tt*16 + (lane&15)]
#define WB_N (480 * 512)

__global__ __launch_bounds__(256) void gru_prep_kernel(
    const float* __restrict__ w_ih, const float* __restrict__ w_hh,
    _Float16* __restrict__ wb)
{
  int n = blockIdx.x * 256 + threadIdx.x;
  if (n >= WB_N) return;
  int i = n & 7, l = (n >> 3) & 63, f = n >> 9;
  int q = l >> 4, col = l & 15;
  int tt, kb, gate;
  if (f < 160)      { tt = f / 10;               kb = f % 10;        gate = 0; }
  else if (f < 320) { int f2 = f - 160; tt = f2 / 10; kb = f2 % 10;  gate = 1; }
  else if (f < 448) { int f3 = f - 320; tt = f3 / 8;  kb = f3 % 8;   gate = 2; }
  else              { int f4 = f - 448; tt = f4 / 2;  kb = 8 + (f4 & 1); gate = 3; }
  int j = (tt & 15) * 16 + col;
  int k = kb * 32 + q * 8 + i;
  float v;
  if (gate == 0)      v = (k < 256) ? w_hh[(0   + j) * 256 + k] : w_ih[(0   + j) * 64 + (k - 256)];
  else if (gate == 1) v = (k < 256) ? w_hh[(256 + j) * 256 + k] : w_ih[(256 + j) * 64 + (k - 256)];
  else if (gate == 2) v = w_hh[(512 + j) * 256 + k];
  else                v = w_ih[(512 + j) * 64 + (k - 256)];
  wb[n] = (_Float16)v;
}

__device__ __forceinline__ float sigm(float v) {
  return __builtin_amdgcn_rcpf(1.0f + __expf(-v));
}
__device__ __forceinline__ float tanh_f(float v) {
  return 1.0f - 2.0f * __builtin_amdgcn_rcpf(1.0f + __expf(2.0f * v));
}

#define MFMA16(a, b, c) __builtin_amdgcn_mfma_f32_16x16x32_f16(a, b, c, 0, 0, 0)

// ---------------- batched MFMA recurrence: 1 block = 16 sequences, 8 waves ----------------
// Wave w owns col-tiles {w, 8+w} of each gate (cols w*16.. and 128+w*16..): each
// A-fragment read feeds 8 MFMAs (was 4 at 16 waves) — A LDS traffic halves.
// n-gate frags in LDS (128 KB); r,z,i frags streamed from L2 (validated in R10).
// Epilogue in-register; h state in 8 named scalars; ONE barrier per step.
__global__ __launch_bounds__(THR) void gru_kernel(
    const float* __restrict__ x,      // [B, T, I]
    const float* __restrict__ b_ih,   // [768]
    const float* __restrict__ b_hh,   // [768]
    const float* __restrict__ w_out,  // [256]
    const float* __restrict__ b_out,  // [1]
    const _Float16* __restrict__ wb,  // packed B fragments
    float* __restrict__ out)          // [T, B]
{
  __shared__ __align__(16) _Float16 H[2][NSEQ][HS];    // 22016 B, double-buffered
  __shared__ __align__(16) _Float16 WN[128 * 512];     // 131072 B: all 16 n-gate tiles
  __shared__ float red[2][NSEQ][8];                    // 1 KB

  const int tid  = threadIdx.x;
  const int lane = tid & 63;
  const int w    = tid >> 6;        // wave 0..7
  const int q    = lane >> 4;       // quad 0..3
  const int col  = lane & 15;
  const int b0   = blockIdx.x * NSEQ;
  const int j1   = w * 16 + col;          // first owned unit
  const int j2   = 128 + w * 16 + col;    // second owned unit

  // ---- stage n-gate frags to LDS (128 KB = 8192 float4, coalesced) ----
  {
    const float4* src = (const float4*)(wb + (size_t)320 * 512);
    float4* dst = (float4*)WN;
    #pragma unroll
    for (int it = 0; it < 16; ++it) dst[tid + it * THR] = src[tid + it * THR];
  }

  // streamed fragment base pointers (loop-invariant, L2-hot). half8 = 16 B; frag = 64 half8.
  const _Float16* wbL = wb + (size_t)lane * 8;
  const half8* pR0 = (const half8*)(wbL + (size_t)((w)     * 10) * 512);
  const half8* pR1 = (const half8*)(wbL + (size_t)((8 + w) * 10) * 512);
  const half8* pZ0 = (const half8*)(wbL + (size_t)(160 + (w)     * 10) * 512);
  const half8* pZ1 = (const half8*)(wbL + (size_t)(160 + (8 + w) * 10) * 512);
  const half8* pI0 = (const half8*)(wbL + (size_t)(448 + (w)     * 2) * 512);
  const half8* pI1 = (const half8*)(wbL + (size_t)(448 + (8 + w) * 2) * 512);

  const float br1  = b_ih[j1] + b_hh[j1];
  const float bz1  = b_ih[256 + j1] + b_hh[256 + j1];
  const float bin1 = b_ih[512 + j1];
  const float bhn1 = b_hh[512 + j1];
  const float br2  = b_ih[j2] + b_hh[j2];
  const float bz2  = b_ih[256 + j2] + b_hh[256 + j2];
  const float bin2 = b_ih[512 + j2];
  const float bhn2 = b_hh[512 + j2];
  const float wo1  = w_out[j1];
  const float wo2  = w_out[j2];
  const float bo   = b_out[0];

  // ---- init: zero H (both buffers), then x(t=0) into H[0] ----
  {
    float4* hz = (float4*)H;
    #pragma unroll
    for (int it = 0; it < 3; ++it) {
      int idx = tid + it * THR;
      if (idx < (int)(sizeof(H) / 16)) hz[idx] = float4{0, 0, 0, 0};
    }
  }
  __syncthreads();
  // two x values per thread: flat idx tid (seqs 0..7) and tid+512 (seqs 8..15)
  const float* xpA = x + (size_t)(b0 + (tid >> 6)) * (NT * NI) + (tid & 63);
  const float* xpB = x + (size_t)(b0 + 8 + (tid >> 6)) * (NT * NI) + (tid & 63);
  H[0][tid >> 6][256 + (tid & 63)]     = (_Float16)xpA[0];
  H[0][8 + (tid >> 6)][256 + (tid & 63)] = (_Float16)xpB[0];
  float h10 = 0, h11 = 0, h12 = 0, h13 = 0;
  float h20 = 0, h21 = 0, h22 = 0, h23 = 0;
  __syncthreads();

  for (int t = 0; t < NT; ++t) {
    const int cur = t & 1, nxt = cur ^ 1;
    float xv0 = 0.0f, xv1 = 0.0f;
    if (t + 1 < NT) {
      xv0 = xpA[(size_t)(t + 1) * 64];
      xv1 = xpB[(size_t)(t + 1) * 64];
    }

    // ---- GEMM: A row = seq = col (validated); 60 MFMAs/wave, 8 indep chains ----
    const _Float16* hrow = &H[cur][col][q * 8];
    floatx4 cR0 = {0, 0, 0, 0}, cR1 = {0, 0, 0, 0};
    floatx4 cZ0 = {0, 0, 0, 0}, cZ1 = {0, 0, 0, 0};
    floatx4 cN0 = {0, 0, 0, 0}, cN1 = {0, 0, 0, 0};
    floatx4 cI0 = {0, 0, 0, 0}, cI1 = {0, 0, 0, 0};
    #pragma unroll
    for (int kb = 0; kb < 8; ++kb) {
      half8 a = *(const half8*)(hrow + kb * 32);
      cR0 = MFMA16(a, pR0[kb * 64], cR0);
      cR1 = MFMA16(a, pR1[kb * 64], cR1);
      cZ0 = MFMA16(a, pZ0[kb * 64], cZ0);
      cZ1 = MFMA16(a, pZ1[kb * 64], cZ1);
      cN0 = MFMA16(a, *(const half8*)&WN[((size_t)(w * 8 + kb)) * 512 + lane * 8], cN0);
      cN1 = MFMA16(a, *(const half8*)&WN[((size_t)((8 + w) * 8 + kb)) * 512 + lane * 8], cN1);
    }
    {
      half8 a = *(const half8*)(hrow + 8 * 32);
      cR0 = MFMA16(a, pR0[8 * 64], cR0);
      cR1 = MFMA16(a, pR1[8 * 64], cR1);
      cZ0 = MFMA16(a, pZ0[8 * 64], cZ0);
      cZ1 = MFMA16(a, pZ1[8 * 64], cZ1);
      cI0 = MFMA16(a, pI0[0], cI0);
      cI1 = MFMA16(a, pI1[0], cI1);
    }
    {
      half8 a = *(const half8*)(hrow + 9 * 32);
      cR0 = MFMA16(a, pR0[9 * 64], cR0);
      cR1 = MFMA16(a, pR1[9 * 64], cR1);
      cZ0 = MFMA16(a, pZ0[9 * 64], cZ0);
      cZ1 = MFMA16(a, pZ1[9 * 64], cZ1);
      cI0 = MFMA16(a, pI0[64], cI0);
      cI1 = MFMA16(a, pI1[64], cI1);
    }

    // ---- in-register epilogue: lane owns (j1, j2) x seqs q*4..q*4+3 ----
#define GATE(m, hv, CR, CZ, CN, CI, BR_, BZ_, BIN_, BHN_, J) { \
    float rr = sigm(CR[m] + BR_); \
    float zz = sigm(CZ[m] + BZ_); \
    float nn = tanh_f(CI[m] + BIN_ + rr * (CN[m] + BHN_)); \
    hv = (1.0f - zz) * nn + zz * hv; \
    H[nxt][q * 4 + (m)][J] = (_Float16)hv; }
    GATE(0, h10, cR0, cZ0, cN0, cI0, br1, bz1, bin1, bhn1, j1)
    GATE(1, h11, cR0, cZ0, cN0, cI0, br1, bz1, bin1, bhn1, j1)
    GATE(2, h12, cR0, cZ0, cN0, cI0, br1, bz1, bin1, bhn1, j1)
    GATE(3, h13, cR0, cZ0, cN0, cI0, br1, bz1, bin1, bhn1, j1)
    GATE(0, h20, cR1, cZ1, cN1, cI1, br2, bz2, bin2, bhn2, j2)
    GATE(1, h21, cR1, cZ1, cN1, cI1, br2, bz2, bin2, bhn2, j2)
    GATE(2, h22, cR1, cZ1, cN1, cI1, br2, bz2, bin2, bhn2, j2)
    GATE(3, h23, cR1, cZ1, cN1, cI1, br2, bz2, bin2, bhn2, j2)
#undef GATE
    if (t + 1 < NT) {
      H[nxt][tid >> 6][256 + (tid & 63)]       = (_Float16)xv0;
      H[nxt][8 + (tid >> 6)][256 + (tid & 63)] = (_Float16)xv1;
    }

    // out-projection: p_m = h1*wo1 + h2*wo2, reduce over 16 cols in-wave
    float p0 = h10 * wo1 + h20 * wo2;
    float p1 = h11 * wo1 + h21 * wo2;
    float p2 = h12 * wo1 + h22 * wo2;
    float p3 = h13 * wo1 + h23 * wo2;
    p0 += __shfl_xor(p0, 1); p1 += __shfl_xor(p1, 1);
    p2 += __shfl_xor(p2, 1); p3 += __shfl_xor(p3, 1);
    p0 += __shfl_xor(p0, 2); p1 += __shfl_xor(p1, 2);
    p2 += __shfl_xor(p2, 2); p3 += __shfl_xor(p3, 2);
    p0 += __shfl_xor(p0, 4); p1 += __shfl_xor(p1, 4);
    p2 += __shfl_xor(p2, 4); p3 += __shfl_xor(p3, 4);
    p0 += __shfl_xor(p0, 8); p1 += __shfl_xor(p1, 8);
    p2 += __shfl_xor(p2, 8); p3 += __shfl_xor(p3, 8);
    if (col == 0) {
      red[cur][q * 4 + 0][w] = p0;
      red[cur][q * 4 + 1][w] = p1;
      red[cur][q * 4 + 2][w] = p2;
      red[cur][q * 4 + 3][w] = p3;
    }
    __syncthreads();   // the single per-step barrier

    // finalize out for step t (threads 0..127; red double-buffered vs t+1 writes)
    if (tid < 128) {
      int s = tid >> 3, e = tid & 7;
      float v = red[cur][s][e];
      v += __shfl_xor(v, 1);
      v += __shfl_xor(v, 2);
      v += __shfl_xor(v, 4);
      if (e == 0) out[t * NB + b0 + s] = v + bo;
    }
  }
}

extern "C" void kernel_launch(void* const* d_in, const int* in_sizes, int n_in,
                              void* d_out, int out_size, void* d_ws, size_t ws_size,
                              hipStream_t stream) {
  const float* x     = (const float*)d_in[0];
  const float* w_ih  = (const float*)d_in[1];
  const float* w_hh  = (const float*)d_in[2];
  const float* b_ih  = (const float*)d_in[3];
  const float* b_hh  = (const float*)d_in[4];
  const float* w_out = (const float*)d_in[5];
  const float* b_out = (const float*)d_in[6];
  float* out = (float*)d_out;

  _Float16* wb = (_Float16*)d_ws;   // 480 KB packed B fragments

  gru_prep_kernel<<<(WB_N + 255) / 256, 256, 0, stream>>>(w_ih, w_hh, wb);
  gru_kernel<<<NBLK, THR, 0, stream>>>(x, b_ih, b_hh, w_out, b_out, wb, out);
}

// Round 13
// 1256.816 us; speedup vs baseline: 2.0809x; 1.3231x over previous
//
#include <hip/hip_runtime.h>

typedef _Float16 half8 __attribute__((ext_vector_type(8)));
typedef _Float16 f16x2 __attribute__((ext_vector_type(2)));
typedef float floatx4 __attribute__((ext_vector_type(4)));

#define NB 256    // batch
#define NT 512    // time
#define NI 64     // input
#define NH 256    // hidden
#define NSEQ 16   // sequences per block
#define NBLK (NB / NSEQ)   // 16 blocks
#define THR 1024           // 16 waves
#define HS 344             // H row stride in f16

// B-fragment pack (VALIDATED R9/R10): 480 frags x 64 lanes x 8 f16.
// Cols: [0,256)=r, [256,512)=z, [512,768)=h_n, [768,1024)=i_n. K: [0,256)=h, [256,320)=x.
// frag f: r: tt*10+kb; z: 160+tt*10+kb; h_n: 320+tt*8+kb (kb<8); i_n: 448+tt*2+(kb-8).
// wb[f*512 + lane*8 + i] = W[k = kb*32 + (lane>>4)*8 + i][n = tt*16 + (lane&15)]
#define WB_N (480 * 512)

__global__ __launch_bounds__(256) void gru_prep_kernel(
    const float* __restrict__ w_ih, const float* __restrict__ w_hh,
    _Float16* __restrict__ wb)
{
  int n = blockIdx.x * 256 + threadIdx.x;
  if (n >= WB_N) return;
  int i = n & 7, l = (n >> 3) & 63, f = n >> 9;
  int q = l >> 4, col = l & 15;
  int tt, kb, gate;
  if (f < 160)      { tt = f / 10;               kb = f % 10;        gate = 0; }
  else if (f < 320) { int f2 = f - 160; tt = f2 / 10; kb = f2 % 10;  gate = 1; }
  else if (f < 448) { int f3 = f - 320; tt = f3 / 8;  kb = f3 % 8;   gate = 2; }
  else              { int f4 = f - 448; tt = f4 / 2;  kb = 8 + (f4 & 1); gate = 3; }
  int j = (tt & 15) * 16 + col;
  int k = kb * 32 + q * 8 + i;
  float v;
  if (gate == 0)      v = (k < 256) ? w_hh[(0   + j) * 256 + k] : w_ih[(0   + j) * 64 + (k - 256)];
  else if (gate == 1) v = (k < 256) ? w_hh[(256 + j) * 256 + k] : w_ih[(256 + j) * 64 + (k - 256)];
  else if (gate == 2) v = w_hh[(512 + j) * 256 + k];
  else                v = w_ih[(512 + j) * 64 + (k - 256)];
  wb[n] = (_Float16)v;
}

__device__ __forceinline__ float sigm(float v) {
  return __builtin_amdgcn_rcpf(1.0f + __expf(-v));
}
__device__ __forceinline__ float tanh_f(float v) {
  return 1.0f - 2.0f * __builtin_amdgcn_rcpf(1.0f + __expf(2.0f * v));
}

#define MFMA16(a, b, c) __builtin_amdgcn_mfma_f32_16x16x32_f16(a, b, c, 0, 0, 0)
#define FDOT(W, X, A) __builtin_amdgcn_fdot2(__builtin_bit_cast(f16x2, W), \
                                             __builtin_bit_cast(f16x2, X), A, false)

// ---------------- batched MFMA recurrence: 1 block = 16 sequences (R10 skeleton) ----------------
// Out-projection REMOVED from the step loop (R10's 256 shfl_xor DS-ops/step + red
// round-trip were ~1500 cyc of LDS-pipe). Instead h_t is dumped to global HD each
// step (8 b128 reads + 8 coalesced dwordx4 stores) and a trivial epilogue kernel
// computes out = HD . w_out.
__global__ __launch_bounds__(THR) void gru_kernel(
    const float* __restrict__ x,      // [B, T, I]
    const float* __restrict__ b_ih,   // [768]
    const float* __restrict__ b_hh,   // [768]
    const _Float16* __restrict__ wb,  // packed B fragments
    _Float16* __restrict__ HD,        // [NT][NB][NH] f16 hidden-state dump
    float* __restrict__ out)          // unused here (kept for symmetry)
{
  __shared__ __align__(16) _Float16 H[2][NSEQ][HS];   // 22016 B, double-buffered
  __shared__ __align__(16) _Float16 WN[8 * 16 * 512]; // 131072 B: n-gate frags

  const int tid  = threadIdx.x;
  const int lane = tid & 63;
  const int w    = tid >> 6;        // wave 0..15
  const int q    = lane >> 4;       // quad 0..3
  const int col  = lane & 15;
  const int b0   = blockIdx.x * NSEQ;
  const int j    = w * 16 + col;    // hidden unit owned in epilogue

  // ---- stage n-gate frags to LDS (128 KB, coalesced float4) ----
  {
    const float4* src = (const float4*)(wb + (size_t)320 * 512);
    float4* dst = (float4*)WN;
    #pragma unroll
    for (int it = 0; it < 8; ++it) dst[tid + it * THR] = src[tid + it * THR];
  }

  // ---- persistent B fragments: 16 named half8 (validated R10) ----
  const _Float16* wbL = wb + (size_t)lane * 8;
#define LBR(k) const half8 BR##k = *(const half8*)(wbL + (size_t)(w * 10 + (k)) * 512);
  LBR(0) LBR(1) LBR(2) LBR(3) LBR(4) LBR(5) LBR(6) LBR(7) LBR(8) LBR(9)
#undef LBR
#define LBZ(k) const half8 BZ##k = *(const half8*)(wbL + (size_t)(160 + w * 10 + (k)) * 512);
  LBZ(0) LBZ(1) LBZ(2) LBZ(3) LBZ(4) LBZ(5)
#undef LBZ
  const half8* sZ6 = (const half8*)(wbL + (size_t)(160 + w * 10 + 6) * 512);
  const half8* sZ7 = (const half8*)(wbL + (size_t)(160 + w * 10 + 7) * 512);
  const half8* sZ8 = (const half8*)(wbL + (size_t)(160 + w * 10 + 8) * 512);
  const half8* sZ9 = (const half8*)(wbL + (size_t)(160 + w * 10 + 9) * 512);
  const half8* sI0 = (const half8*)(wbL + (size_t)(448 + w * 2 + 0) * 512);
  const half8* sI1 = (const half8*)(wbL + (size_t)(448 + w * 2 + 1) * 512);

  const float br   = b_ih[j] + b_hh[j];
  const float bz   = b_ih[256 + j] + b_hh[256 + j];
  const float bin_ = b_ih[512 + j];
  const float bhn  = b_hh[512 + j];

  // ---- init: zero H (both buffers), then x(t=0) into H[0] ----
  {
    float4* hz = (float4*)H;
    #pragma unroll
    for (int it = 0; it < 2; ++it) {
      int idx = tid + it * THR;
      if (idx < (int)(sizeof(H) / 16)) hz[idx] = float4{0, 0, 0, 0};
    }
  }
  __syncthreads();
  H[0][tid >> 6][256 + (tid & 63)] =
      (_Float16)x[(size_t)(b0 + (tid >> 6)) * (NT * NI) + (tid & 63)];
  float h0 = 0.0f, h1 = 0.0f, h2 = 0.0f, h3 = 0.0f;
  const float* xp = x + (size_t)(b0 + (tid >> 6)) * (NT * NI) + 64 + (tid & 63);
  __syncthreads();

  for (int t = 0; t < NT; ++t) {
    const int cur = t & 1, nxt = cur ^ 1;
    half8 SZ6 = *sZ6, SZ7 = *sZ7, SZ8 = *sZ8, SZ9 = *sZ9, SI0i = *sI0, SI1i = *sI1;
    float xv = 0.0f;
    if (t + 1 < NT) xv = xp[(size_t)t * 64];

    // ---- dump h_{t-1} (h-part of H[cur]) to HD[t-1]: 8 b128 reads + 8 stores ----
    if (t > 0 && tid < 512) {
      int row = tid >> 5, ch = tid & 31;
      float4 hv = *(const float4*)&H[cur][row][ch * 8];
      *(float4*)(HD + ((size_t)(t - 1) * NB + b0 + row) * NH + ch * 8) = hv;
    }

    // ---- GEMM: A row = seq = col (validated), 30 MFMAs/wave ----
    const _Float16* hrow = &H[cur][col][q * 8];
    floatx4 cR = {0, 0, 0, 0}, cZ = {0, 0, 0, 0}, cN = {0, 0, 0, 0}, cI = {0, 0, 0, 0};
#define KBN(k, BZk) { \
    half8 a = *(const half8*)(hrow + (k) * 32); \
    cR = MFMA16(a, BR##k, cR); \
    cZ = MFMA16(a, BZk, cZ); \
    cN = MFMA16(a, *(const half8*)&WN[(w * 8 + (k)) * 512 + lane * 8], cN); }
    KBN(0, BZ0) KBN(1, BZ1) KBN(2, BZ2) KBN(3, BZ3) KBN(4, BZ4) KBN(5, BZ5)
    KBN(6, SZ6) KBN(7, SZ7)
#undef KBN
    { half8 a = *(const half8*)(hrow + 8 * 32);
      cR = MFMA16(a, BR8, cR); cZ = MFMA16(a, SZ8, cZ); cI = MFMA16(a, SI0i, cI); }
    { half8 a = *(const half8*)(hrow + 9 * 32);
      cR = MFMA16(a, BR9, cR); cZ = MFMA16(a, SZ9, cZ); cI = MFMA16(a, SI1i, cI); }

    // ---- in-register epilogue: lane owns (j, seqs q*4..q*4+3) ----
#define GATE(m, hvar) { \
    float rr = sigm(cR[m] + br); \
    float zz = sigm(cZ[m] + bz); \
    float nn = tanh_f(cI[m] + bin_ + rr * (cN[m] + bhn)); \
    hvar = (1.0f - zz) * nn + zz * hvar; \
    H[nxt][q * 4 + (m)][j] = (_Float16)hvar; }
    GATE(0, h0) GATE(1, h1) GATE(2, h2) GATE(3, h3)
#undef GATE
    if (t + 1 < NT) H[nxt][tid >> 6][256 + (tid & 63)] = (_Float16)xv;

    __syncthreads();   // the single per-step barrier
  }

  // ---- final dump: h_{NT-1} lives in H[0] (NT even) ----
  if (tid < 512) {
    int row = tid >> 5, ch = tid & 31;
    float4 hv = *(const float4*)&H[0][row][ch * 8];
    *(float4*)(HD + ((size_t)(NT - 1) * NB + b0 + row) * NH + ch * 8) = hv;
  }
}

// ---------------- epilogue: out[t][b] = HD[t][b][:] . w_out + b_out ----------------
__global__ __launch_bounds__(256) void gru_out_kernel(
    const _Float16* __restrict__ HD, const float* __restrict__ w_out,
    const float* __restrict__ b_out, float* __restrict__ out)
{
  __shared__ __align__(16) _Float16 WL[NH];
  int tid = threadIdx.x;
  WL[tid] = (_Float16)w_out[tid];
  __syncthreads();
  int gid = blockIdx.x * 256 + tid;          // gid = t*NB + b
  const float4* hp = (const float4*)(HD + (size_t)gid * NH);
  const float4* wp = (const float4*)WL;
  float acc = 0.0f;
  #pragma unroll
  for (int i = 0; i < NH / 8; ++i) {
    float4 hv = hp[i];
    float4 wv = wp[i];
    acc = FDOT(hv.x, wv.x, acc);
    acc = FDOT(hv.y, wv.y, acc);
    acc = FDOT(hv.z, wv.z, acc);
    acc = FDOT(hv.w, wv.w, acc);
  }
  out[gid] = acc + b_out[0];
}

extern "C" void kernel_launch(void* const* d_in, const int* in_sizes, int n_in,
                              void* d_out, int out_size, void* d_ws, size_t ws_size,
                              hipStream_t stream) {
  const float* x     = (const float*)d_in[0];
  const float* w_ih  = (const float*)d_in[1];
  const float* w_hh  = (const float*)d_in[2];
  const float* b_ih  = (const float*)d_in[3];
  const float* b_hh  = (const float*)d_in[4];
  const float* w_out = (const float*)d_in[5];
  const float* b_out = (const float*)d_in[6];
  float* out = (float*)d_out;

  _Float16* wb = (_Float16*)d_ws;            // 480 KB packed B fragments
  _Float16* HD = wb + WB_N;                  // 64 MB hidden-state dump (16B-aligned)

  gru_prep_kernel<<<(WB_N + 255) / 256, 256, 0, stream>>>(w_ih, w_hh, wb);
  gru_kernel<<<NBLK, THR, 0, stream>>>(x, b_ih, b_hh, wb, HD, out);
  gru_out_kernel<<<(NT * NB) / 256, 256, 0, stream>>>(HD, w_out, b_out, out);
}